// Round 15
// baseline (850.357 us; speedup 1.0000x reference)
//
#include <hip/hip_runtime.h>

// ---- problem constants ----
// BATCH=4096 HORIZON=64 HIST_DIM=256 HW=512 EMBED=96 LATENT=128
// out = [z_pred (4096,64,128) | x_pred (4096,64,32) | z_target (4096,64,128)] f32
#define XP_OFF 33554432L
#define ZT_OFF 41943040L

// padded bf16 weight layout in ws (row stride = ODD multiple of 64B lines -> no L2
// channel camping; verified r13: 831->631us from this alone):
//   W0: 512 rows x stride 288 (K=256, 576B = 9 lines)   @ 0
//   W1: 512 rows x stride 544 (K=512, 1088B = 17 lines) @ 147456
//   W2: 512 rows x stride 544                           @ 425984
//   W3:  96 rows x stride 544                           @ 704512
#define W0_OFF 0
#define W1_OFF 147456
#define W2_OFF 425984
#define W3_OFF 704512
#define ZK_BYTE_OFF 1513472L

typedef __attribute__((ext_vector_type(8))) short bf16x8;   // 8 bf16 = 4 VGPRs
typedef __attribute__((ext_vector_type(4))) float f32x4;    // MFMA accum

__device__ __forceinline__ unsigned short f2bf(float f){
  union { float ff; unsigned int uu; } c; c.ff = f;
  unsigned int u = c.uu;
  return (unsigned short)((u + 0x7FFFu + ((u >> 16) & 1u)) >> 16);  // RNE
}

// ---------------- weight f32 -> bf16 convert (padded layout) ----------------
__global__ void cvt_kernel(const float* __restrict__ w0, const float* __restrict__ w1,
                           const float* __restrict__ w2, const float* __restrict__ w3,
                           unsigned short* __restrict__ o){
  int i = blockIdx.x * 256 + threadIdx.x;
  if (i < 131072){                                   // W0: 512x256
    int r = i >> 8, c = i & 255;
    o[W0_OFF + r*288 + c] = f2bf(w0[i]);
  } else if (i < 393216){                            // W1: 512x512
    int j = i - 131072; int r = j >> 9, c = j & 511;
    o[W1_OFF + r*544 + c] = f2bf(w1[j]);
  } else if (i < 655360){                            // W2: 512x512
    int j = i - 393216; int r = j >> 9, c = j & 511;
    o[W2_OFF + r*544 + c] = f2bf(w2[j]);
  } else if (i < 704512){                            // W3: 96x512
    int j = i - 655360; int r = j >> 9, c = j & 511;
    o[W3_OFF + r*544 + c] = f2bf(w3[j]);
  }
}

// ---------------- fused 4-layer encoder ----------------
// M=128 tile: halves L2 weight re-streaming (6.2 -> 3.1 GB, the dominant floor term).
// Inner loop is r13's PROVEN 631us structure byte-for-byte (depth-1 b-prefetch, a[4]
// upfront, unroll 1, padded W stride) + nrow0 offset. 8 waves (512 thr), wave = 64 rows
// x 128 cols (NT=8, MT=4) -- same per-wave regs as r13 (~252 unified, no spill).
// act LDS: 128 rows x 512 cols bf16 (128 KB) -> 1 block/CU, 8 waves/CU (same occ as r13).
// MFMA swapped operands: D = mfma(Wfrag, ACTfrag) -> lane = (row m=ml, 4 consecutive cols).
template<int K, int WS, int NT, int MT>
__device__ __forceinline__ void gemm_tile(const unsigned short* __restrict__ W,
                                          const unsigned short* act,
                                          int lane, int nrow0, int ncol0,
                                          f32x4 (&acc)[NT][MT]){
  const int kl = (lane >> 4) << 3;   // k offset of this lane within 32-chunk
  const int ml = lane & 15;
  const unsigned short* wp = W + (ncol0 + ml)*WS + kl;   // W row (ncol0+ml), col kl
  bf16x8 bcur[NT], bnxt[NT];
#pragma unroll
  for (int nt = 0; nt < NT; ++nt)
    bcur[nt] = *(const bf16x8*)(wp + nt*16*WS);
#pragma unroll 1
  for (int kc = 0; kc < K/32; ++kc){
    if (kc + 1 < K/32){                               // depth-1 W prefetch (in flight over MFMA)
#pragma unroll
      for (int nt = 0; nt < NT; ++nt)
        bnxt[nt] = *(const bf16x8*)(wp + nt*16*WS + (kc+1)*32);
    }
    const int kk = kc*32 + kl;
    bf16x8 a[MT];                                     // all a ds_reads issued upfront
#pragma unroll
    for (int mt = 0; mt < MT; ++mt){
      int m = nrow0 + mt*16 + ml;
      int byt = ((m << 10) + (kk << 1)) ^ ((m & 7) << 4);
      a[mt] = *(const bf16x8*)((const char*)act + byt);
    }
#pragma unroll
    for (int mt = 0; mt < MT; ++mt)                   // mt-outer: progressive lgkmcnt
#pragma unroll
      for (int nt = 0; nt < NT; ++nt)
        acc[nt][mt] = __builtin_amdgcn_mfma_f32_16x16x32_bf16(bcur[nt], a[mt], acc[nt][mt], 0, 0, 0);
#pragma unroll
    for (int nt = 0; nt < NT; ++nt) bcur[nt] = bnxt[nt];
  }
}

// epilogue: lane holds row m = nrow0+mt*16+ml, cols n0..n0+3 (n0 = ncol0+nt*16+rl)
template<int NT, int MT>
__device__ __forceinline__ void epi_lds(f32x4 (&acc)[NT][MT], const float* __restrict__ bias,
                                        int nrow0, int ncol0, int lane, unsigned short* act){
  const int ml = lane & 15;
  const int rl = (lane >> 4) << 2;
#pragma unroll
  for (int nt = 0; nt < NT; ++nt){
    int n0 = ncol0 + nt*16 + rl;
    float4 bn = *(const float4*)(bias + n0);
#pragma unroll
    for (int mt = 0; mt < MT; ++mt){
      int m = nrow0 + mt*16 + ml;
      float v0 = acc[nt][mt][0] + bn.x; v0 = v0 > 0.f ? v0 : 0.f;
      float v1 = acc[nt][mt][1] + bn.y; v1 = v1 > 0.f ? v1 : 0.f;
      float v2 = acc[nt][mt][2] + bn.z; v2 = v2 > 0.f ? v2 : 0.f;
      float v3 = acc[nt][mt][3] + bn.w; v3 = v3 > 0.f ? v3 : 0.f;
      ushort4 p; p.x = f2bf(v0); p.y = f2bf(v1); p.z = f2bf(v2); p.w = f2bf(v3);
      int byt = ((m << 10) + (n0 << 1)) ^ ((m & 7) << 4);   // 8B-aligned, swizzle flips bit4
      *(ushort4*)((char*)act + byt) = p;
    }
  }
}

__global__ __launch_bounds__(512, 2) void enc_kernel(
    const float* __restrict__ histk, const float* __restrict__ histn,
    const unsigned short* __restrict__ wb,
    const float* __restrict__ b0, const float* __restrict__ b1,
    const float* __restrict__ b2, const float* __restrict__ b3,
    float* __restrict__ zk, float* __restrict__ out){
  __shared__ __align__(16) unsigned short act[128*512];   // 128 KB -> 1 block/CU, 8 waves
  const int tid  = threadIdx.x;
  const int lane = tid & 63;
  const int wave = tid >> 6;           // 0..7
  const int wr   = wave >> 2;          // row group 0..1 (64 rows each)
  const int wc   = wave & 3;           // col group 0..3 (128 cols each)
  const int blk  = blockIdx.x;
  const bool is_zk = (blk < 32);       // 4096 history_k rows = 32 blocks of 128
  const long r0 = (long)blk * 128;
  const float* __restrict__ src = is_zk ? (histk + r0*256) : (histn + (r0 - 4096)*256);
  const float4* src4 = (const float4*)src;

  // stage input tile (128x256 f32 -> bf16 LDS), emit "cur" state cols 224..255
#pragma unroll 4
  for (int j = 0; j < 16; ++j){
    int vidx = j*512 + tid;                      // 8192 float4 total
    float4 v = src4[vidx];
    int r  = vidx >> 6;
    int k0 = (vidx & 63) << 2;
    ushort4 p;
    p.x = f2bf(v.x); p.y = f2bf(v.y); p.z = f2bf(v.z); p.w = f2bf(v.w);
    int byt = ((r << 10) + (k0 << 1)) ^ ((r & 7) << 4);
    *(ushort4*)((char*)act + byt) = p;
    if (k0 >= 224){                              // hist[..., -32:] -> z[..., :32]
      long rg = r0 + r;
      int c = k0 - 224;
      if (is_zk) *(float4*)(zk + rg*128 + c) = v;
      else       *(float4*)(out + ZT_OFF + (rg - 4096)*128 + c) = v;
    }
  }
  __syncthreads();

  { // layer 0: 256 -> 512
    f32x4 acc[8][4];
#pragma unroll
    for (int i = 0; i < 8; ++i)
#pragma unroll
      for (int j = 0; j < 4; ++j) acc[i][j] = (f32x4){0.f,0.f,0.f,0.f};
    gemm_tile<256,288,8,4>(wb + W0_OFF, act, lane, wr*64, wc*128, acc);
    __syncthreads();
    epi_lds<8,4>(acc, b0, wr*64, wc*128, lane, act);
  }
  __syncthreads();
  { // layer 1: 512 -> 512
    f32x4 acc[8][4];
#pragma unroll
    for (int i = 0; i < 8; ++i)
#pragma unroll
      for (int j = 0; j < 4; ++j) acc[i][j] = (f32x4){0.f,0.f,0.f,0.f};
    gemm_tile<512,544,8,4>(wb + W1_OFF, act, lane, wr*64, wc*128, acc);
    __syncthreads();
    epi_lds<8,4>(acc, b1, wr*64, wc*128, lane, act);
  }
  __syncthreads();
  { // layer 2: 512 -> 512
    f32x4 acc[8][4];
#pragma unroll
    for (int i = 0; i < 8; ++i)
#pragma unroll
      for (int j = 0; j < 4; ++j) acc[i][j] = (f32x4){0.f,0.f,0.f,0.f};
    gemm_tile<512,544,8,4>(wb + W2_OFF, act, lane, wr*64, wc*128, acc);
    __syncthreads();
    epi_lds<8,4>(acc, b2, wr*64, wc*128, lane, act);
  }
  __syncthreads();
  { // layer 3: 512 -> 96 (no relu). 6 waves = 2 row-groups (64 rows) x 3 col-groups (32).
    if (wave < 6){
      const int wr3 = wave & 1;        // row group 0..1 -> all 128 rows (r6 lesson)
      const int wc3 = wave >> 1;       // col group 0..2 -> 96 cols
      f32x4 acc[2][4];
#pragma unroll
      for (int i = 0; i < 2; ++i)
#pragma unroll
        for (int j = 0; j < 4; ++j) acc[i][j] = (f32x4){0.f,0.f,0.f,0.f};
      gemm_tile<512,544,2,4>(wb + W3_OFF, act, lane, wr3*64, wc3*32, acc);
      const int ml = lane & 15, rl = (lane >> 4) << 2;
#pragma unroll
      for (int nt = 0; nt < 2; ++nt){
        int n0 = wc3*32 + nt*16 + rl;            // embed col base (mult of 4)
        float4 bn = *(const float4*)(b3 + n0);
#pragma unroll
        for (int mt = 0; mt < 4; ++mt){
          int m = wr3*64 + mt*16 + ml;
          long rg = r0 + m;
          float4 v;
          v.x = acc[nt][mt][0] + bn.x;
          v.y = acc[nt][mt][1] + bn.y;
          v.z = acc[nt][mt][2] + bn.z;
          v.w = acc[nt][mt][3] + bn.w;
          if (is_zk) *(float4*)(zk + rg*128 + 32 + n0) = v;
          else       *(float4*)(out + ZT_OFF + (rg - 4096)*128 + 32 + n0) = v;
        }
      }
    }
  }
}

// ---------------- fp32 linear scan: z <- z@A^T + u@B^T ----------------
__global__ __launch_bounds__(256, 2) void scan_kernel(
    const float* __restrict__ A, const float* __restrict__ B,
    const float* __restrict__ u, const float* __restrict__ zkv,
    float* __restrict__ out){
  __shared__ __align__(16) float zbuf[2][2][128];
  __shared__ __align__(16) float ubuf[1024];
  const int tid = threadIdx.x;
  const int lr  = tid >> 7;            // which of 2 batch rows
  const int l   = tid & 127;           // latent index
  const long row = (long)blockIdx.x * 2 + lr;

  float Ar[128];                       // A_W[l][0..127] -> fully static-indexed (VGPRs!)
  const float4* A4 = (const float4*)A;
#pragma unroll
  for (int j4 = 0; j4 < 32; ++j4){     // FULL unroll: static indices -> registers, no scratch
    float4 v = A4[l*32 + j4];
    Ar[4*j4] = v.x; Ar[4*j4+1] = v.y; Ar[4*j4+2] = v.z; Ar[4*j4+3] = v.w;
  }
  float Br[8];                         // B_W[l][0..7]
  {
    const float4* B4 = (const float4*)B;
    float4 v0 = B4[l*2], v1 = B4[l*2+1];
    Br[0]=v0.x; Br[1]=v0.y; Br[2]=v0.z; Br[3]=v0.w;
    Br[4]=v1.x; Br[5]=v1.y; Br[6]=v1.z; Br[7]=v1.w;
  }
  ((float4*)ubuf)[tid] = ((const float4*)(u + (long)blockIdx.x*1024))[tid];  // 2 rows of u_seq
  zbuf[0][lr][l] = zkv[row*128 + l];
  __syncthreads();

  const long zp = row*8192 + l;
  const long xp = XP_OFF + row*2048 + l;
  int cur = 0;
#pragma unroll 1
  for (int t = 0; t < 64; ++t){
    const float* zc = zbuf[cur][lr];
    float acc = 0.f;
#pragma unroll
    for (int j4 = 0; j4 < 32; ++j4){
      float4 zv = ((const float4*)zc)[j4];     // broadcast LDS read
      acc += Ar[4*j4]*zv.x + Ar[4*j4+1]*zv.y + Ar[4*j4+2]*zv.z + Ar[4*j4+3]*zv.w;
    }
    const float4* uu = (const float4*)(ubuf + lr*512 + t*8);
    float4 u0 = uu[0], u1 = uu[1];
    acc += Br[0]*u0.x + Br[1]*u0.y + Br[2]*u0.z + Br[3]*u0.w
         + Br[4]*u1.x + Br[5]*u1.y + Br[6]*u1.z + Br[7]*u1.w;
    zbuf[cur^1][lr][l] = acc;
    out[zp + t*128] = acc;                     // z_pred[row][t][l]
    if (l < 32) out[xp + t*32] = acc;          // x_pred[row][t][l]
    __syncthreads();
    cur ^= 1;
  }
}

extern "C" void kernel_launch(void* const* d_in, const int* in_sizes, int n_in,
                              void* d_out, int out_size, void* d_ws, size_t ws_size,
                              hipStream_t stream){
  const float* histk = (const float*)d_in[0];
  const float* useq  = (const float*)d_in[1];
  const float* histn = (const float*)d_in[2];
  const float* W0 = (const float*)d_in[3];
  const float* b0 = (const float*)d_in[4];
  const float* W1 = (const float*)d_in[5];
  const float* b1 = (const float*)d_in[6];
  const float* W2 = (const float*)d_in[7];
  const float* b2 = (const float*)d_in[8];
  const float* W3 = (const float*)d_in[9];
  const float* b3 = (const float*)d_in[10];
  const float* A  = (const float*)d_in[11];
  const float* B  = (const float*)d_in[12];
  float* out = (float*)d_out;

  // ws layout: [0, 1513472) padded bf16 weights; then z_k (4096x128 f32, 2 MB). ~3.5 MB
  unsigned short* wb = (unsigned short*)d_ws;
  float* zk = (float*)((char*)d_ws + ZK_BYTE_OFF);

  cvt_kernel <<<2752, 256, 0, stream>>>(W0, W1, W2, W3, wb);
  enc_kernel <<<2080, 512, 0, stream>>>(histk, histn, wb,
                                        b0, b1, b2, b3, zk, out);
  scan_kernel<<<2048, 256, 0, stream>>>(A, B, useq, zk, out);
}

// Round 16
// 742.861 us; speedup vs baseline: 1.1447x; 1.1447x over previous
//
#include <hip/hip_runtime.h>

// ---- problem constants ----
// BATCH=4096 HORIZON=64 HIST_DIM=256 HW=512 EMBED=96 LATENT=128
// out = [z_pred (4096,64,128) | x_pred (4096,64,32) | z_target (4096,64,128)] f32
#define XP_OFF 33554432L
#define ZT_OFF 41943040L

// padded bf16 weight layout in ws (row stride = ODD multiple of 64B lines -> no L2
// channel camping; verified r13: 831->631us from this alone):
//   W0: 512 rows x stride 288 (K=256, 576B = 9 lines)   @ 0
//   W1: 512 rows x stride 544 (K=512, 1088B = 17 lines) @ 147456
//   W2: 512 rows x stride 544                           @ 425984
//   W3:  96 rows x stride 544                           @ 704512
#define W0_OFF 0
#define W1_OFF 147456
#define W2_OFF 425984
#define W3_OFF 704512
#define ZK_BYTE_OFF 1513472L

typedef __attribute__((ext_vector_type(8))) short bf16x8;   // 8 bf16 = 4 VGPRs
typedef __attribute__((ext_vector_type(4))) float f32x4;    // MFMA accum

__device__ __forceinline__ unsigned short f2bf(float f){
  union { float ff; unsigned int uu; } c; c.ff = f;
  unsigned int u = c.uu;
  return (unsigned short)((u + 0x7FFFu + ((u >> 16) & 1u)) >> 16);  // RNE
}

// ---------------- weight f32 -> bf16 convert (padded layout) ----------------
__global__ void cvt_kernel(const float* __restrict__ w0, const float* __restrict__ w1,
                           const float* __restrict__ w2, const float* __restrict__ w3,
                           unsigned short* __restrict__ o){
  int i = blockIdx.x * 256 + threadIdx.x;
  if (i < 131072){                                   // W0: 512x256
    int r = i >> 8, c = i & 255;
    o[W0_OFF + r*288 + c] = f2bf(w0[i]);
  } else if (i < 393216){                            // W1: 512x512
    int j = i - 131072; int r = j >> 9, c = j & 511;
    o[W1_OFF + r*544 + c] = f2bf(w1[j]);
  } else if (i < 655360){                            // W2: 512x512
    int j = i - 393216; int r = j >> 9, c = j & 511;
    o[W2_OFF + r*544 + c] = f2bf(w2[j]);
  } else if (i < 704512){                            // W3: 96x512
    int j = i - 655360; int r = j >> 9, c = j & 511;
    o[W3_OFF + r*544 + c] = f2bf(w3[j]);
  }
}

// ---------------- fused 4-layer encoder ----------------
// r16 = r10 geometry (8 waves/512thr, wave = 64 rows x 64 cols, NT=4 MT=4, a[4] upfront,
// depth-1 b-prefetch, launch_bounds(512,4) -> 128-reg cap, PROVEN fit: r10 VGPR=64+64AGPR,
// occupancy 40.8%) + r13 padded W stride (PROVEN +24%: kills L2 channel camping).
// First combination of {4 waves/SIMD TLP} x {padding}. r13 had padding at 2 waves/SIMD;
// r10 had 4 waves/SIMD without padding (L2 camping ate the latency-hiding benefit).
// act LDS: 64 rows x 512 cols bf16 (64 KB) -> 2 blocks/CU, 16 waves/CU.
// MFMA swapped operands: D = mfma(Wfrag, ACTfrag) -> lane = (row m=ml, 4 consecutive cols).
template<int K, int WS, int NT, int MT>
__device__ __forceinline__ void gemm_tile(const unsigned short* __restrict__ W,
                                          const unsigned short* act,
                                          int lane, int ncol0, f32x4 (&acc)[NT][MT]){
  const int kl = (lane >> 4) << 3;   // k offset of this lane within 32-chunk
  const int ml = lane & 15;
  const unsigned short* wp = W + (ncol0 + ml)*WS + kl;   // W row (ncol0+ml), col kl
  bf16x8 bcur[NT], bnxt[NT];
#pragma unroll
  for (int nt = 0; nt < NT; ++nt)
    bcur[nt] = *(const bf16x8*)(wp + nt*16*WS);
#pragma unroll 1
  for (int kc = 0; kc < K/32; ++kc){
    if (kc + 1 < K/32){                               // depth-1 W prefetch (in flight over MFMA)
#pragma unroll
      for (int nt = 0; nt < NT; ++nt)
        bnxt[nt] = *(const bf16x8*)(wp + nt*16*WS + (kc+1)*32);
    }
    const int kk = kc*32 + kl;
    bf16x8 a[MT];                                     // all a ds_reads issued upfront
#pragma unroll
    for (int mt = 0; mt < MT; ++mt){
      int m = mt*16 + ml;
      int byt = ((m << 10) + (kk << 1)) ^ ((m & 7) << 4);
      a[mt] = *(const bf16x8*)((const char*)act + byt);
    }
#pragma unroll
    for (int mt = 0; mt < MT; ++mt)                   // mt-outer: progressive lgkmcnt
#pragma unroll
      for (int nt = 0; nt < NT; ++nt)
        acc[nt][mt] = __builtin_amdgcn_mfma_f32_16x16x32_bf16(bcur[nt], a[mt], acc[nt][mt], 0, 0, 0);
#pragma unroll
    for (int nt = 0; nt < NT; ++nt) bcur[nt] = bnxt[nt];
  }
}

// epilogue: lane holds row m = mt*16+ml, cols n0..n0+3 (n0 = ncol0+nt*16+rl)
template<int NT, int MT>
__device__ __forceinline__ void epi_lds(f32x4 (&acc)[NT][MT], const float* __restrict__ bias,
                                        int ncol0, int lane, unsigned short* act){
  const int ml = lane & 15;
  const int rl = (lane >> 4) << 2;
#pragma unroll
  for (int nt = 0; nt < NT; ++nt){
    int n0 = ncol0 + nt*16 + rl;
    float4 bn = *(const float4*)(bias + n0);
#pragma unroll
    for (int mt = 0; mt < MT; ++mt){
      int m = mt*16 + ml;
      float v0 = acc[nt][mt][0] + bn.x; v0 = v0 > 0.f ? v0 : 0.f;
      float v1 = acc[nt][mt][1] + bn.y; v1 = v1 > 0.f ? v1 : 0.f;
      float v2 = acc[nt][mt][2] + bn.z; v2 = v2 > 0.f ? v2 : 0.f;
      float v3 = acc[nt][mt][3] + bn.w; v3 = v3 > 0.f ? v3 : 0.f;
      ushort4 p; p.x = f2bf(v0); p.y = f2bf(v1); p.z = f2bf(v2); p.w = f2bf(v3);
      int byt = ((m << 10) + (n0 << 1)) ^ ((m & 7) << 4);   // 8B-aligned, swizzle flips bit4
      *(ushort4*)((char*)act + byt) = p;
    }
  }
}

__global__ __launch_bounds__(512, 4) void enc_kernel(
    const float* __restrict__ histk, const float* __restrict__ histn,
    const unsigned short* __restrict__ wb,
    const float* __restrict__ b0, const float* __restrict__ b1,
    const float* __restrict__ b2, const float* __restrict__ b3,
    float* __restrict__ zk, float* __restrict__ out){
  __shared__ __align__(16) unsigned short act[64*512];   // 64 KB -> 2 blocks/CU
  const int tid  = threadIdx.x;
  const int lane = tid & 63;
  const int wave = tid >> 6;           // 0..7, col group (64 cols each)
  const int blk  = blockIdx.x;
  const bool is_zk = (blk < 64);       // 4096 history_k rows = 64 blocks of 64
  const long r0 = (long)blk * 64;
  const float* __restrict__ src = is_zk ? (histk + r0*256) : (histn + (r0 - 4096)*256);
  const float4* src4 = (const float4*)src;

  // stage input tile (64x256 f32 -> bf16 LDS), emit "cur" state cols 224..255
#pragma unroll 4
  for (int j = 0; j < 8; ++j){
    int vidx = j*512 + tid;                      // 4096 float4 total
    float4 v = src4[vidx];
    int r  = vidx >> 6;
    int k0 = (vidx & 63) << 2;
    ushort4 p;
    p.x = f2bf(v.x); p.y = f2bf(v.y); p.z = f2bf(v.z); p.w = f2bf(v.w);
    int byt = ((r << 10) + (k0 << 1)) ^ ((r & 7) << 4);
    *(ushort4*)((char*)act + byt) = p;
    if (k0 >= 224){                              // hist[..., -32:] -> z[..., :32]
      long rg = r0 + r;
      int c = k0 - 224;
      if (is_zk) *(float4*)(zk + rg*128 + c) = v;
      else       *(float4*)(out + ZT_OFF + (rg - 4096)*128 + c) = v;
    }
  }
  __syncthreads();

  { // layer 0: 256 -> 512, wave owns cols [wave*64, wave*64+64)
    f32x4 acc[4][4];
#pragma unroll
    for (int i = 0; i < 4; ++i)
#pragma unroll
      for (int j = 0; j < 4; ++j) acc[i][j] = (f32x4){0.f,0.f,0.f,0.f};
    gemm_tile<256,288,4,4>(wb + W0_OFF, act, lane, wave*64, acc);
    __syncthreads();
    epi_lds<4,4>(acc, b0, wave*64, lane, act);
  }
  __syncthreads();
  { // layer 1: 512 -> 512
    f32x4 acc[4][4];
#pragma unroll
    for (int i = 0; i < 4; ++i)
#pragma unroll
      for (int j = 0; j < 4; ++j) acc[i][j] = (f32x4){0.f,0.f,0.f,0.f};
    gemm_tile<512,544,4,4>(wb + W1_OFF, act, lane, wave*64, acc);
    __syncthreads();
    epi_lds<4,4>(acc, b1, wave*64, lane, act);
  }
  __syncthreads();
  { // layer 2: 512 -> 512
    f32x4 acc[4][4];
#pragma unroll
    for (int i = 0; i < 4; ++i)
#pragma unroll
      for (int j = 0; j < 4; ++j) acc[i][j] = (f32x4){0.f,0.f,0.f,0.f};
    gemm_tile<512,544,4,4>(wb + W2_OFF, act, lane, wave*64, acc);
    __syncthreads();
    epi_lds<4,4>(acc, b2, wave*64, lane, act);
  }
  __syncthreads();
  { // layer 3: 512 -> 96 (no relu), waves 0..2 cover 96 cols (32 each), all 64 rows
    if (wave < 3){
      f32x4 acc[2][4];
#pragma unroll
      for (int i = 0; i < 2; ++i)
#pragma unroll
        for (int j = 0; j < 4; ++j) acc[i][j] = (f32x4){0.f,0.f,0.f,0.f};
      gemm_tile<512,544,2,4>(wb + W3_OFF, act, lane, wave*32, acc);
      const int ml = lane & 15, rl = (lane >> 4) << 2;
#pragma unroll
      for (int nt = 0; nt < 2; ++nt){
        int n0 = wave*32 + nt*16 + rl;           // embed col base (mult of 4)
        float4 bn = *(const float4*)(b3 + n0);
#pragma unroll
        for (int mt = 0; mt < 4; ++mt){
          int m = mt*16 + ml;
          long rg = r0 + m;
          float4 v;
          v.x = acc[nt][mt][0] + bn.x;
          v.y = acc[nt][mt][1] + bn.y;
          v.z = acc[nt][mt][2] + bn.z;
          v.w = acc[nt][mt][3] + bn.w;
          if (is_zk) *(float4*)(zk + rg*128 + 32 + n0) = v;
          else       *(float4*)(out + ZT_OFF + (rg - 4096)*128 + 32 + n0) = v;
        }
      }
    }
  }
}

// ---------------- fp32 linear scan: z <- z@A^T + u@B^T ----------------
__global__ __launch_bounds__(256, 2) void scan_kernel(
    const float* __restrict__ A, const float* __restrict__ B,
    const float* __restrict__ u, const float* __restrict__ zkv,
    float* __restrict__ out){
  __shared__ __align__(16) float zbuf[2][2][128];
  __shared__ __align__(16) float ubuf[1024];
  const int tid = threadIdx.x;
  const int lr  = tid >> 7;            // which of 2 batch rows
  const int l   = tid & 127;           // latent index
  const long row = (long)blockIdx.x * 2 + lr;

  float Ar[128];                       // A_W[l][0..127] -> fully static-indexed (VGPRs!)
  const float4* A4 = (const float4*)A;
#pragma unroll
  for (int j4 = 0; j4 < 32; ++j4){     // FULL unroll: static indices -> registers, no scratch
    float4 v = A4[l*32 + j4];
    Ar[4*j4] = v.x; Ar[4*j4+1] = v.y; Ar[4*j4+2] = v.z; Ar[4*j4+3] = v.w;
  }
  float Br[8];                         // B_W[l][0..7]
  {
    const float4* B4 = (const float4*)B;
    float4 v0 = B4[l*2], v1 = B4[l*2+1];
    Br[0]=v0.x; Br[1]=v0.y; Br[2]=v0.z; Br[3]=v0.w;
    Br[4]=v1.x; Br[5]=v1.y; Br[6]=v1.z; Br[7]=v1.w;
  }
  ((float4*)ubuf)[tid] = ((const float4*)(u + (long)blockIdx.x*1024))[tid];  // 2 rows of u_seq
  zbuf[0][lr][l] = zkv[row*128 + l];
  __syncthreads();

  const long zp = row*8192 + l;
  const long xp = XP_OFF + row*2048 + l;
  int cur = 0;
#pragma unroll 1
  for (int t = 0; t < 64; ++t){
    const float* zc = zbuf[cur][lr];
    float acc = 0.f;
#pragma unroll
    for (int j4 = 0; j4 < 32; ++j4){
      float4 zv = ((const float4*)zc)[j4];     // broadcast LDS read
      acc += Ar[4*j4]*zv.x + Ar[4*j4+1]*zv.y + Ar[4*j4+2]*zv.z + Ar[4*j4+3]*zv.w;
    }
    const float4* uu = (const float4*)(ubuf + lr*512 + t*8);
    float4 u0 = uu[0], u1 = uu[1];
    acc += Br[0]*u0.x + Br[1]*u0.y + Br[2]*u0.z + Br[3]*u0.w
         + Br[4]*u1.x + Br[5]*u1.y + Br[6]*u1.z + Br[7]*u1.w;
    zbuf[cur^1][lr][l] = acc;
    out[zp + t*128] = acc;                     // z_pred[row][t][l]
    if (l < 32) out[xp + t*32] = acc;          // x_pred[row][t][l]
    __syncthreads();
    cur ^= 1;
  }
}

extern "C" void kernel_launch(void* const* d_in, const int* in_sizes, int n_in,
                              void* d_out, int out_size, void* d_ws, size_t ws_size,
                              hipStream_t stream){
  const float* histk = (const float*)d_in[0];
  const float* useq  = (const float*)d_in[1];
  const float* histn = (const float*)d_in[2];
  const float* W0 = (const float*)d_in[3];
  const float* b0 = (const float*)d_in[4];
  const float* W1 = (const float*)d_in[5];
  const float* b1 = (const float*)d_in[6];
  const float* W2 = (const float*)d_in[7];
  const float* b2 = (const float*)d_in[8];
  const float* W3 = (const float*)d_in[9];
  const float* b3 = (const float*)d_in[10];
  const float* A  = (const float*)d_in[11];
  const float* B  = (const float*)d_in[12];
  float* out = (float*)d_out;

  // ws layout: [0, 1513472) padded bf16 weights; then z_k (4096x128 f32, 2 MB). ~3.5 MB
  unsigned short* wb = (unsigned short*)d_ws;
  float* zk = (float*)((char*)d_ws + ZK_BYTE_OFF);

  cvt_kernel <<<2752, 256, 0, stream>>>(W0, W1, W2, W3, wb);
  enc_kernel <<<4160, 512, 0, stream>>>(histk, histn, wb,
                                        b0, b1, b2, b3, zk, out);
  scan_kernel<<<2048, 256, 0, stream>>>(A, B, useq, zk, out);
}

// Round 17
// 716.548 us; speedup vs baseline: 1.1867x; 1.0367x over previous
//
#include <hip/hip_runtime.h>

// ---- problem constants ----
// BATCH=4096 HORIZON=64 HIST_DIM=256 HW=512 EMBED=96 LATENT=128
// out = [z_pred (4096,64,128) | x_pred (4096,64,32) | z_target (4096,64,128)] f32
#define XP_OFF 33554432L
#define ZT_OFF 41943040L

// padded bf16 weight layout in ws (row stride = ODD multiple of 64B lines -> no L2
// channel camping; verified r13: 831->631us from this alone):
#define W0_OFF 0
#define W1_OFF 147456
#define W2_OFF 425984
#define W3_OFF 704512
#define ZK_BYTE_OFF 1513472L

typedef __attribute__((ext_vector_type(8))) short bf16x8;   // 8 bf16 = 4 VGPRs
typedef __attribute__((ext_vector_type(4))) float f32x4;    // MFMA accum

__device__ __forceinline__ unsigned short f2bf(float f){
  union { float ff; unsigned int uu; } c; c.ff = f;
  unsigned int u = c.uu;
  return (unsigned short)((u + 0x7FFFu + ((u >> 16) & 1u)) >> 16);  // RNE
}

// ---------------- weight f32 -> bf16 convert (padded layout) ----------------
__global__ void cvt_kernel(const float* __restrict__ w0, const float* __restrict__ w1,
                           const float* __restrict__ w2, const float* __restrict__ w3,
                           unsigned short* __restrict__ o){
  int i = blockIdx.x * 256 + threadIdx.x;
  if (i < 131072){                                   // W0: 512x256
    int r = i >> 8, c = i & 255;
    o[W0_OFF + r*288 + c] = f2bf(w0[i]);
  } else if (i < 393216){                            // W1: 512x512
    int j = i - 131072; int r = j >> 9, c = j & 511;
    o[W1_OFF + r*544 + c] = f2bf(w1[j]);
  } else if (i < 655360){                            // W2: 512x512
    int j = i - 393216; int r = j >> 9, c = j & 511;
    o[W2_OFF + r*544 + c] = f2bf(w2[j]);
  } else if (i < 704512){                            // W3: 96x512
    int j = i - 655360; int r = j >> 9, c = j & 511;
    o[W3_OFF + r*544 + c] = f2bf(w3[j]);
  }
}

// ---------------- fused 4-layer encoder ----------------
// r16 shell (8 waves/512thr, wave = 64 rows x 64 cols, NT=4 MT=4, a[4] upfront,
// launch_bounds(512,4), padded W stride, 64KB LDS, 2 blocks/CU) with ONE change:
// even/odd b0/b1 buffers (manual kc+=2 unroll) REPLACE the bcur<-bnxt rotation --
// same 32 VGPR for b, same prefetch distance, minus 16 v_mov per kc (VALU tax cut).
// MFMA swapped operands: D = mfma(Wfrag, ACTfrag) -> lane = (row m=ml, 4 consecutive cols).
template<int K, int WS, int NT, int MT>
__device__ __forceinline__ void gemm_tile(const unsigned short* __restrict__ W,
                                          const unsigned short* act,
                                          int lane, int ncol0, f32x4 (&acc)[NT][MT]){
  const int kl = (lane >> 4) << 3;   // k offset of this lane within 32-chunk
  const int ml = lane & 15;
  const unsigned short* wp = W + (ncol0 + ml)*WS + kl;   // W row (ncol0+ml), col kl
  constexpr int NK = K/32;           // 8 or 16 (always even)
  bf16x8 b0[NT], b1[NT];

  auto loadB = [&](bf16x8 (&bb)[NT], int kc){
#pragma unroll
    for (int nt = 0; nt < NT; ++nt)
      bb[nt] = *(const bf16x8*)(wp + nt*16*WS + kc*32);
  };
  auto half = [&](bf16x8 (&bb)[NT], int kc){
    const int kk = kc*32 + kl;
    bf16x8 a[MT];                                     // a ds_reads issued upfront
#pragma unroll
    for (int mt = 0; mt < MT; ++mt){
      int m = mt*16 + ml;
      int byt = ((m << 10) + (kk << 1)) ^ ((m & 7) << 4);
      a[mt] = *(const bf16x8*)((const char*)act + byt);
    }
#pragma unroll
    for (int mt = 0; mt < MT; ++mt)                   // mt-outer: progressive lgkmcnt
#pragma unroll
      for (int nt = 0; nt < NT; ++nt)
        acc[nt][mt] = __builtin_amdgcn_mfma_f32_16x16x32_bf16(bb[nt], a[mt], acc[nt][mt], 0, 0, 0);
  };

  loadB(b0, 0);
#pragma unroll 1
  for (int kc = 0; kc < NK; kc += 2){
    loadB(b1, kc+1);                  // prefetch kc+1 (in flight over MFMA(kc))
    half(b0, kc);
    if (kc + 2 < NK) loadB(b0, kc+2); // prefetch kc+2 (in flight over MFMA(kc+1))
    half(b1, kc+1);
  }
}

// epilogue: lane holds row m = mt*16+ml, cols n0..n0+3 (n0 = ncol0+nt*16+rl)
template<int NT, int MT>
__device__ __forceinline__ void epi_lds(f32x4 (&acc)[NT][MT], const float* __restrict__ bias,
                                        int ncol0, int lane, unsigned short* act){
  const int ml = lane & 15;
  const int rl = (lane >> 4) << 2;
#pragma unroll
  for (int nt = 0; nt < NT; ++nt){
    int n0 = ncol0 + nt*16 + rl;
    float4 bn = *(const float4*)(bias + n0);
#pragma unroll
    for (int mt = 0; mt < MT; ++mt){
      int m = mt*16 + ml;
      float v0 = acc[nt][mt][0] + bn.x; v0 = v0 > 0.f ? v0 : 0.f;
      float v1 = acc[nt][mt][1] + bn.y; v1 = v1 > 0.f ? v1 : 0.f;
      float v2 = acc[nt][mt][2] + bn.z; v2 = v2 > 0.f ? v2 : 0.f;
      float v3 = acc[nt][mt][3] + bn.w; v3 = v3 > 0.f ? v3 : 0.f;
      ushort4 p; p.x = f2bf(v0); p.y = f2bf(v1); p.z = f2bf(v2); p.w = f2bf(v3);
      int byt = ((m << 10) + (n0 << 1)) ^ ((m & 7) << 4);   // 8B-aligned, swizzle flips bit4
      *(ushort4*)((char*)act + byt) = p;
    }
  }
}

__global__ __launch_bounds__(512, 4) void enc_kernel(
    const float* __restrict__ histk, const float* __restrict__ histn,
    const unsigned short* __restrict__ wb,
    const float* __restrict__ b0, const float* __restrict__ b1,
    const float* __restrict__ b2, const float* __restrict__ b3,
    float* __restrict__ zk, float* __restrict__ out){
  __shared__ __align__(16) unsigned short act[64*512];   // 64 KB -> 2 blocks/CU
  const int tid  = threadIdx.x;
  const int lane = tid & 63;
  const int wave = tid >> 6;           // 0..7, col group (64 cols each)
  const int blk  = blockIdx.x;
  const bool is_zk = (blk < 64);       // 4096 history_k rows = 64 blocks of 64
  const long r0 = (long)blk * 64;
  const float* __restrict__ src = is_zk ? (histk + r0*256) : (histn + (r0 - 4096)*256);
  const float4* src4 = (const float4*)src;

  // stage input tile (64x256 f32 -> bf16 LDS), emit "cur" state cols 224..255
#pragma unroll 4
  for (int j = 0; j < 8; ++j){
    int vidx = j*512 + tid;                      // 4096 float4 total
    float4 v = src4[vidx];
    int r  = vidx >> 6;
    int k0 = (vidx & 63) << 2;
    ushort4 p;
    p.x = f2bf(v.x); p.y = f2bf(v.y); p.z = f2bf(v.z); p.w = f2bf(v.w);
    int byt = ((r << 10) + (k0 << 1)) ^ ((r & 7) << 4);
    *(ushort4*)((char*)act + byt) = p;
    if (k0 >= 224){                              // hist[..., -32:] -> z[..., :32]
      long rg = r0 + r;
      int c = k0 - 224;
      if (is_zk) *(float4*)(zk + rg*128 + c) = v;
      else       *(float4*)(out + ZT_OFF + (rg - 4096)*128 + c) = v;
    }
  }
  __syncthreads();

  { // layer 0: 256 -> 512, wave owns cols [wave*64, wave*64+64)
    f32x4 acc[4][4];
#pragma unroll
    for (int i = 0; i < 4; ++i)
#pragma unroll
      for (int j = 0; j < 4; ++j) acc[i][j] = (f32x4){0.f,0.f,0.f,0.f};
    gemm_tile<256,288,4,4>(wb + W0_OFF, act, lane, wave*64, acc);
    __syncthreads();
    epi_lds<4,4>(acc, b0, wave*64, lane, act);
  }
  __syncthreads();
  { // layer 1: 512 -> 512
    f32x4 acc[4][4];
#pragma unroll
    for (int i = 0; i < 4; ++i)
#pragma unroll
      for (int j = 0; j < 4; ++j) acc[i][j] = (f32x4){0.f,0.f,0.f,0.f};
    gemm_tile<512,544,4,4>(wb + W1_OFF, act, lane, wave*64, acc);
    __syncthreads();
    epi_lds<4,4>(acc, b1, wave*64, lane, act);
  }
  __syncthreads();
  { // layer 2: 512 -> 512
    f32x4 acc[4][4];
#pragma unroll
    for (int i = 0; i < 4; ++i)
#pragma unroll
      for (int j = 0; j < 4; ++j) acc[i][j] = (f32x4){0.f,0.f,0.f,0.f};
    gemm_tile<512,544,4,4>(wb + W2_OFF, act, lane, wave*64, acc);
    __syncthreads();
    epi_lds<4,4>(acc, b2, wave*64, lane, act);
  }
  __syncthreads();
  { // layer 3: 512 -> 96 (no relu), waves 0..2 cover 96 cols (32 each), all 64 rows
    if (wave < 3){
      f32x4 acc[2][4];
#pragma unroll
      for (int i = 0; i < 2; ++i)
#pragma unroll
        for (int j = 0; j < 4; ++j) acc[i][j] = (f32x4){0.f,0.f,0.f,0.f};
      gemm_tile<512,544,2,4>(wb + W3_OFF, act, lane, wave*32, acc);
      const int ml = lane & 15, rl = (lane >> 4) << 2;
#pragma unroll
      for (int nt = 0; nt < 2; ++nt){
        int n0 = wave*32 + nt*16 + rl;           // embed col base (mult of 4)
        float4 bn = *(const float4*)(b3 + n0);
#pragma unroll
        for (int mt = 0; mt < 4; ++mt){
          int m = mt*16 + ml;
          long rg = r0 + m;
          float4 v;
          v.x = acc[nt][mt][0] + bn.x;
          v.y = acc[nt][mt][1] + bn.y;
          v.z = acc[nt][mt][2] + bn.z;
          v.w = acc[nt][mt][3] + bn.w;
          if (is_zk) *(float4*)(zk + rg*128 + 32 + n0) = v;
          else       *(float4*)(out + ZT_OFF + (rg - 4096)*128 + 32 + n0) = v;
        }
      }
    }
  }
}

// ---------------- fp32 linear scan: z <- z@A^T + u@B^T ----------------
// r17: 4-way split accumulator (breaks the 32-deep dependent FMA chain -> 8-deep x4).
__global__ __launch_bounds__(256, 2) void scan_kernel(
    const float* __restrict__ A, const float* __restrict__ B,
    const float* __restrict__ u, const float* __restrict__ zkv,
    float* __restrict__ out){
  __shared__ __align__(16) float zbuf[2][2][128];
  __shared__ __align__(16) float ubuf[1024];
  const int tid = threadIdx.x;
  const int lr  = tid >> 7;            // which of 2 batch rows
  const int l   = tid & 127;           // latent index
  const long row = (long)blockIdx.x * 2 + lr;

  float Ar[128];                       // A_W[l][0..127] -> fully static-indexed (VGPRs!)
  const float4* A4 = (const float4*)A;
#pragma unroll
  for (int j4 = 0; j4 < 32; ++j4){     // FULL unroll: static indices -> registers, no scratch
    float4 v = A4[l*32 + j4];
    Ar[4*j4] = v.x; Ar[4*j4+1] = v.y; Ar[4*j4+2] = v.z; Ar[4*j4+3] = v.w;
  }
  float Br[8];                         // B_W[l][0..7]
  {
    const float4* B4 = (const float4*)B;
    float4 v0 = B4[l*2], v1 = B4[l*2+1];
    Br[0]=v0.x; Br[1]=v0.y; Br[2]=v0.z; Br[3]=v0.w;
    Br[4]=v1.x; Br[5]=v1.y; Br[6]=v1.z; Br[7]=v1.w;
  }
  ((float4*)ubuf)[tid] = ((const float4*)(u + (long)blockIdx.x*1024))[tid];  // 2 rows of u_seq
  zbuf[0][lr][l] = zkv[row*128 + l];
  __syncthreads();

  const long zp = row*8192 + l;
  const long xp = XP_OFF + row*2048 + l;
  int cur = 0;
#pragma unroll 1
  for (int t = 0; t < 64; ++t){
    const float* zc = zbuf[cur][lr];
    float a0 = 0.f, a1 = 0.f, a2 = 0.f, a3 = 0.f;   // 4 independent chains
#pragma unroll
    for (int j4 = 0; j4 < 32; j4 += 4){
      float4 z0 = ((const float4*)zc)[j4+0];
      float4 z1 = ((const float4*)zc)[j4+1];
      float4 z2 = ((const float4*)zc)[j4+2];
      float4 z3 = ((const float4*)zc)[j4+3];
      a0 += Ar[4*j4+ 0]*z0.x + Ar[4*j4+ 1]*z0.y + Ar[4*j4+ 2]*z0.z + Ar[4*j4+ 3]*z0.w;
      a1 += Ar[4*j4+ 4]*z1.x + Ar[4*j4+ 5]*z1.y + Ar[4*j4+ 6]*z1.z + Ar[4*j4+ 7]*z1.w;
      a2 += Ar[4*j4+ 8]*z2.x + Ar[4*j4+ 9]*z2.y + Ar[4*j4+10]*z2.z + Ar[4*j4+11]*z2.w;
      a3 += Ar[4*j4+12]*z3.x + Ar[4*j4+13]*z3.y + Ar[4*j4+14]*z3.z + Ar[4*j4+15]*z3.w;
    }
    const float4* uu = (const float4*)(ubuf + lr*512 + t*8);
    float4 u0 = uu[0], u1 = uu[1];
    float ub = Br[0]*u0.x + Br[1]*u0.y + Br[2]*u0.z + Br[3]*u0.w
             + Br[4]*u1.x + Br[5]*u1.y + Br[6]*u1.z + Br[7]*u1.w;
    float acc = ((a0 + a1) + (a2 + a3)) + ub;
    zbuf[cur^1][lr][l] = acc;
    out[zp + t*128] = acc;                     // z_pred[row][t][l]
    if (l < 32) out[xp + t*32] = acc;          // x_pred[row][t][l]
    __syncthreads();
    cur ^= 1;
  }
}

extern "C" void kernel_launch(void* const* d_in, const int* in_sizes, int n_in,
                              void* d_out, int out_size, void* d_ws, size_t ws_size,
                              hipStream_t stream){
  const float* histk = (const float*)d_in[0];
  const float* useq  = (const float*)d_in[1];
  const float* histn = (const float*)d_in[2];
  const float* W0 = (const float*)d_in[3];
  const float* b0 = (const float*)d_in[4];
  const float* W1 = (const float*)d_in[5];
  const float* b1 = (const float*)d_in[6];
  const float* W2 = (const float*)d_in[7];
  const float* b2 = (const float*)d_in[8];
  const float* W3 = (const float*)d_in[9];
  const float* b3 = (const float*)d_in[10];
  const float* A  = (const float*)d_in[11];
  const float* B  = (const float*)d_in[12];
  float* out = (float*)d_out;

  // ws layout: [0, 1513472) padded bf16 weights; then z_k (4096x128 f32, 2 MB). ~3.5 MB
  unsigned short* wb = (unsigned short*)d_ws;
  float* zk = (float*)((char*)d_ws + ZK_BYTE_OFF);

  cvt_kernel <<<2752, 256, 0, stream>>>(W0, W1, W2, W3, wb);
  enc_kernel <<<4160, 512, 0, stream>>>(histk, histn, wb,
                                        b0, b1, b2, b3, zk, out);
  scan_kernel<<<2048, 256, 0, stream>>>(A, B, useq, zk, out);
}